// Round 14
// baseline (291.428 us; speedup 1.0000x reference)
//
#include <hip/hip_runtime.h>

#define LTAG 64
#define BPB 16   // batch columns per block; grid = B/BPB = 16 blocks, 1 wave each
#define L2E 1.4426950408889634f
#define LN2 0.6931471805599453f

typedef float f32x4v __attribute__((ext_vector_type(4)));
typedef short s16x8 __attribute__((ext_vector_type(8)));
typedef int i32x4 __attribute__((ext_vector_type(4)));

typedef const __attribute__((address_space(1))) unsigned gas_u32;
typedef __attribute__((address_space(3))) unsigned las_u32;

__device__ __forceinline__ float exp2_fast(float x) { return __builtin_amdgcn_exp2f(x); }
__device__ __forceinline__ float log2_fast(float x) { return __builtin_amdgcn_logf(x); }
__device__ __forceinline__ int bperm_i(int abytes, int v) {
    return __builtin_amdgcn_ds_bpermute(abytes, v);
}
// bf16 pair pack, pure integer round-half-up (r13-validated; the cvt_pk
// inline asm it replaced was the r10-r12 NaN source).
__device__ __forceinline__ int pack_bf16(float lo, float hi) {
    const unsigned ul = __float_as_uint(lo) + 0x8000u;
    const unsigned uh = __float_as_uint(hi) + 0x8000u;
    return (int)((ul >> 16) | (uh & 0xffff0000u));
}
__device__ __forceinline__ float bf16_lo(int w) { return __int_as_float(w << 16); }
__device__ __forceinline__ float bf16_hi(int w) {
    return __int_as_float((int)((unsigned)w & 0xffff0000u));
}

// ROUND-14 — r13 (validated batch-blocked MFMA recurrence, absmax 16.0) with
// the x-stream moved onto a global_load_lds ring with HAND-COUNTED vmcnt.
//
// r13 counters: 1016 cy/step, MFMA ~30cy + VALU ~127cy + ~850cy STALL with
// 1 wave/CU — the compiler parks ~full HBM latency (~900cy) on the chain via
// pessimal vmcnt placement for the register x-ring (r6 diagnosis, purest
// form). Fix: x staged 8 steps ahead into a 16-slot LDS ring by
// __builtin_amdgcn_global_load_lds (no VGPR result -> compiler emits no
// waits for it); the ONLY wait is our asm s_waitcnt vmcnt(28): with <=32
// staging loads in flight, it provably drains only loads issued >=7 steps
// (~2000cy) earlier -> zero stall by construction. ds_read of x_{t+1}
// issues during step t (lgkmcnt auto-counted by compiler).
// Numerics are BIT-IDENTICAL to r13 (same ops, same order): absmax must
// reproduce 16.0 exactly — built-in regression check.
//
// Ring layout (slot = t&15, 4KB): byte (c,w) holds x_t[c][n], n*4 = w ^
// ((c&7)<<4)  [16B-granule XOR swizzle -> ~2-way-conflict reads; T21:
// linear LDS dest + inverse-swizzled GLOBAL source]. Staging instr i,
// lane l: batch cb=4i+(l>>4), quad nq=(l&15)^(cb&7); dest = slot+i*1024 +
// l*16 (HW rule). Reader lane(g,c): quad (64RT+16g)^((c&7)<<4) ^= rows
// 16RT+4g..+3 of batch c.
//
// Everything else r13-verbatim: V'=(E^T V)(x)G, 8 mfma_16x16x32_bf16 (4RT x
// 2KS chained), register-only bperm repack (16 bperm, step-invariant
// addresses), per-column exact pow2 rescale every 4 steps (eb clamped),
// final step t=T-1 in log domain with c2 (tag-B exact).
__global__ __launch_bounds__(64) void crf_forward_kernel(
    const float* __restrict__ X, const float* __restrict__ trans,
    float* __restrict__ out, int T) {
    const int lane = threadIdx.x;
    const int c = lane & 15;   // batch column within block
    const int g = lane >> 4;   // 4-lane row group
    const int b0 = blockIdx.x * BPB;
    const size_t bstr = (size_t)T * LTAG;
    const float* xc = X + (size_t)(b0 + c) * bstr;  // init/final reads only

    __shared__ __align__(16) float xring[16 * 1024];  // 16 slots x 4KB
    __shared__ __align__(16) short vl[BPB][80];
    __shared__ float shl[BPB];

    // ---- staging base pointers (per-lane, 4 instrs per slot) ----
    const float* gp[4];
#pragma unroll
    for (int i = 0; i < 4; ++i) {
        const int cb = 4 * i + g;                  // batch this lane stages
        const int nq = c ^ (g | (4 * (i & 1)));    // tag quad (inverse swz)
        gp[i] = X + (size_t)(b0 + cb) * bstr + nq * 4;
    }

// issue 4 global_load_lds for slot (t_&15) <- x_{min(t_,T-1)}
#define STAGE(t_)                                                             \
    {                                                                         \
        const int tcl = (t_) < T ? (t_) : T - 1;                              \
        las_u32* ld = (las_u32*)(xring + (((t_) & 15) << 10));                \
        _Pragma("unroll") for (int i = 0; i < 4; ++i)                         \
            __builtin_amdgcn_global_load_lds(                                 \
                (gas_u32*)(gp[i] + (size_t)tcl * 64), ld + (i << 8), 16, 0, 0);\
    }
// read x_{t_} rows 16RT+4g..+3 of batch c into XV[0..3]
#define XREAD(t_, XV)                                                         \
    {                                                                         \
        const char* sl =                                                      \
            (const char*)xring + (((t_) & 15) << 12) + (c << 8);              \
        _Pragma("unroll") for (int RT = 0; RT < 4; ++RT)                      \
            XV[RT] = *(const f32x4v*)(sl +                                    \
                                      ((RT * 64 + g * 16) ^ ((c & 7) << 4))); \
    }

    // prologue: slots 1..8 in flight before anything else (overlaps init)
    STAGE(1); STAGE(2); STAGE(3); STAGE(4);
    STAGE(5); STAGE(6); STAGE(7); STAGE(8);

    // ---- constant A-frags: A[m][k] = E^T[m][k] = exp2(trans[k][m]*L2E) ----
    i32x4 Af[4][2];
#pragma unroll
    for (int RT = 0; RT < 4; ++RT)
#pragma unroll
        for (int KS = 0; KS < 2; ++KS) {
            int q[4];
#pragma unroll
            for (int i = 0; i < 4; ++i) {
                const int k0 = 32 * KS + 8 * g + 2 * i;
                const int m = 16 * RT + c;
                q[i] = pack_bf16(exp2_fast(trans[k0 * LTAG + m] * L2E),
                                 exp2_fast(trans[(k0 + 1) * LTAG + m] * L2E));
            }
            Af[RT][KS] = (i32x4){q[0], q[1], q[2], q[3]};
        }

    // ---- init B = V_1: V1[k][c] = exp2((trans[0][k] + x_0[c][k])*L2E) ----
    i32x4 Bf[2];
#pragma unroll
    for (int KS = 0; KS < 2; ++KS) {
        int q[4];
#pragma unroll
        for (int i = 0; i < 4; ++i) {
            const int k0 = 32 * KS + 8 * g + 2 * i;
            q[i] = pack_bf16(exp2_fast((trans[k0] + xc[k0]) * L2E),
                             exp2_fast((trans[k0 + 1] + xc[k0 + 1]) * L2E));
        }
        Bf[KS] = (i32x4){q[0], q[1], q[2], q[3]};
    }

    // slot 1 ready (oldest 4 of <=32 outstanding), read x_1
    asm volatile("s_waitcnt vmcnt(28)" ::: "memory");
    __builtin_amdgcn_sched_barrier(0);
    f32x4v XA[4], XB[4];
    XREAD(1, XA);

    const int adrA = ((((2 * g) & 3) << 4) | c) << 2;
    const int adrB = ((((2 * g + 1) & 3) << 4) | c) << 2;
    float SH = 0.0f;

// one recurrence step t_ consuming XC (=x_{t_}), prefetching XN (=x_{t_+1})
#define SUBSTEP(t_, XC, XN, RESC)                                             \
    {                                                                         \
        /* D = E^T * V : 4 independent 2-chains (r13-validated layouts) */    \
        f32x4v acc[4];                                                        \
        _Pragma("unroll") for (int RT = 0; RT < 4; ++RT) {                    \
            f32x4v z = {0.f, 0.f, 0.f, 0.f};                                  \
            z = __builtin_amdgcn_mfma_f32_16x16x32_bf16(                      \
                __builtin_bit_cast(s16x8, Af[RT][0]),                         \
                __builtin_bit_cast(s16x8, Bf[0]), z, 0, 0, 0);                \
            acc[RT] = __builtin_amdgcn_mfma_f32_16x16x32_bf16(                \
                __builtin_bit_cast(s16x8, Af[RT][1]),                         \
                __builtin_bit_cast(s16x8, Bf[1]), z, 0, 0, 0);                \
        }                                                                     \
        /* stage x_{t_+8}; counted wait proves slot t_+1 landed (issued */    \
        /* >=7 steps ago); never waits on fresh loads */                      \
        STAGE((t_) + 8);                                                      \
        asm volatile("s_waitcnt vmcnt(28)" ::: "memory");                     \
        __builtin_amdgcn_sched_barrier(0);                                    \
        XREAD((t_) + 1, XN);                                                  \
        /* G-scale (x from regs read last step; exp2 hoists under MFMA) */    \
        _Pragma("unroll") for (int RT = 0; RT < 4; ++RT)                      \
        _Pragma("unroll") for (int j = 0; j < 4; ++j)                         \
            acc[RT][j] *= exp2_fast(XC[RT][j] * L2E);                         \
        if (RESC) {                                                           \
            /* per-column EXACT pow2 rescale (full column max via 2 shfl) */  \
            float m = acc[0][0];                                              \
            _Pragma("unroll") for (int RT = 0; RT < 4; ++RT)                  \
            _Pragma("unroll") for (int j = 0; j < 4; ++j)                     \
                m = fmaxf(m, acc[RT][j]);                                     \
            m = fmaxf(m, __shfl_xor(m, 16));                                  \
            m = fmaxf(m, __shfl_xor(m, 32));                                  \
            int eb = (__float_as_int(m) >> 23) & 0xff;                        \
            eb = eb < 1 ? 1 : (eb > 254 ? 254 : eb);                          \
            const float fac = __int_as_float((254 - eb) << 23);               \
            _Pragma("unroll") for (int RT = 0; RT < 4; ++RT)                  \
            _Pragma("unroll") for (int j = 0; j < 4; ++j) acc[RT][j] *= fac;  \
            SH += (float)(eb - 127);                                          \
        }                                                                     \
        /* repack D -> next B (registers only; r13-validated mapping) */      \
        int pk[4][2];                                                         \
        _Pragma("unroll") for (int RT = 0; RT < 4; ++RT) {                    \
            pk[RT][0] = pack_bf16(acc[RT][0], acc[RT][1]);                    \
            pk[RT][1] = pack_bf16(acc[RT][2], acc[RT][3]);                    \
        }                                                                     \
        _Pragma("unroll") for (int KS = 0; KS < 2; ++KS) {                    \
            const int ra0 = bperm_i(adrA, pk[2 * KS][0]);                     \
            const int ra1 = bperm_i(adrA, pk[2 * KS][1]);                     \
            const int ra2 = bperm_i(adrA, pk[2 * KS + 1][0]);                 \
            const int ra3 = bperm_i(adrA, pk[2 * KS + 1][1]);                 \
            const int rb0 = bperm_i(adrB, pk[2 * KS][0]);                     \
            const int rb1 = bperm_i(adrB, pk[2 * KS][1]);                     \
            const int rb2 = bperm_i(adrB, pk[2 * KS + 1][0]);                 \
            const int rb3 = bperm_i(adrB, pk[2 * KS + 1][1]);                 \
            const bool hi = g >= 2;                                           \
            Bf[KS] = (i32x4){hi ? ra2 : ra0, hi ? ra3 : ra1,                  \
                             hi ? rb2 : rb0, hi ? rb3 : rb1};                 \
        }                                                                     \
    }

    int t = 1;
    for (; t + 3 <= T - 2; t += 4) {
        SUBSTEP(t + 0, XA, XB, false);
        SUBSTEP(t + 1, XB, XA, false);
        SUBSTEP(t + 2, XA, XB, false);
        SUBSTEP(t + 3, XB, XA, true);
    }
    if (t <= T - 2) { SUBSTEP(t, XA, XB, ((t & 3) == 0)); ++t; }
    if (t <= T - 2) { SUBSTEP(t, XB, XA, ((t & 3) == 0)); ++t; }
    if (t <= T - 2) { SUBSTEP(t, XA, XB, ((t & 3) == 0)); ++t; }
#undef SUBSTEP
#undef STAGE
#undef XREAD

    // ================= final step t = T-1 (log domain, c2) =================
#pragma unroll
    for (int KS = 0; KS < 2; ++KS)
        *(i32x4*)(&vl[c][32 * KS + 8 * g]) = Bf[KS];
    shl[c] = SH;  // identical across the 4 lanes of column c
    __syncthreads();  // full fence (guards cross-lane LDS RAW — r11 lesson)

    const int n = lane;  // output tag
    float c2n = -3.0e38f;
#pragma unroll
    for (int p = 0; p < LTAG; ++p)
        c2n = fmaxf(c2n, trans[p * LTAG + n] * L2E);
    float er[LTAG];
#pragma unroll
    for (int p = 0; p < LTAG; ++p)
        er[p] = exp2_fast(trans[p * LTAG + n] * L2E - c2n);  // Etr[:,B]==1

    for (int b = 0; b < BPB; ++b) {
        float s0 = 0.f, s1 = 0.f, s2 = 0.f, s3 = 0.f;
#pragma unroll
        for (int p = 0; p < LTAG; p += 4) {
            const int w0 = *(const int*)(&vl[b][p]);  // uniform broadcast
            const int w1 = *(const int*)(&vl[b][p + 2]);
            s0 = fmaf(bf16_lo(w0), er[p + 0], s0);
            s1 = fmaf(bf16_hi(w0), er[p + 1], s1);
            s2 = fmaf(bf16_lo(w1), er[p + 2], s2);
            s3 = fmaf(bf16_hi(w1), er[p + 3], s3);
        }
        float s = (s0 + s1) + (s2 + s3);
        s = fmaxf(s, 1e-30f);  // pathological column stays finite-diagnosable
        const float xl = X[(size_t)(b0 + b) * bstr + (size_t)(T - 1) * LTAG + n];
        out[(b0 + b) * LTAG + n] = (log2_fast(s) + fmaf(xl, L2E, c2n) + shl[b]) * LN2;
    }
}

extern "C" void kernel_launch(void* const* d_in, const int* in_sizes, int n_in,
                              void* d_out, int out_size, void* d_ws, size_t ws_size,
                              hipStream_t stream) {
    const float* X = (const float*)d_in[0];
    const float* trans = (const float*)d_in[1];
    float* out = (float*)d_out;

    const int B = out_size / LTAG;           // 256
    const int T = in_sizes[0] / (B * LTAG);  // 512

    crf_forward_kernel<<<B / BPB, 64, 0, stream>>>(X, trans, out, T);
}